// Round 8
// baseline (153.798 us; speedup 1.0000x reference)
//
#include <hip/hip_runtime.h>
#include <hip/hip_fp16.h>

#define HH 512
#define WW 512
#define HW (HH*WW)
#define EPV 1e-20f

// R17: 8 cols/lane, full 512-col rows per wave (was 3 strips x 4 cols/lane).
// Evidence: controllable budget is prep ~42 + ncc ~33 us (fill 43us is the
// harness workspace poison, fixed). Lane-work efficiency was 34%/36% due to
// strip waste (1.5x prep, 1.5x ncc w/ 8-of-64-lane third strip) + vertical
// halo. 8col/lane: zero col waste, winC 7bp/8cols (was /4), winR 8bp/8cols
// (was 5/4). prep vertical-first for the mean (raw fifo doubles as the
// subtract source; winC-output ring eliminated). fp16 intermediates kept
// (R16: port-bound fix, absmax 0.0). Grids: prep 1280 waves (5/CU), ncc
// 1536 (6/CU) -- single residency batch each at launch_bounds(64,2).
// Keeps: XCD-chunked ncc swizzle, winR-at-emit, 2-slack fifos everywhere,
// barrier-free, per-z wsum + fin kernel.

__device__ __forceinline__ float bpl(int addr, float v) {
    return __int_as_float(__builtin_amdgcn_ds_bpermute(addr, __float_as_int(v)));
}
__device__ __forceinline__ int rcl(int r) { return min(max(r, 0), HH - 1); }

__device__ __forceinline__ float4 h2f4(uint2 r) {
    __half2 lo = *(__half2*)&r.x, hi = *(__half2*)&r.y;
    float2 a = __half22float2(lo), b = __half22float2(hi);
    return make_float4(a.x, a.y, b.x, b.y);
}
__device__ __forceinline__ uint2 f2h4(float4 v) {
    __half2 lo = __floats2half2_rn(v.x, v.y);
    __half2 hi = __floats2half2_rn(v.z, v.w);
    uint2 r;
    r.x = *(unsigned int*)&lo;
    r.y = *(unsigned int*)&hi;
    return r;
}
__device__ __forceinline__ uint4 pack8(float4 a, float4 b) {
    uint2 lo = f2h4(a), hi = f2h4(b);
    return make_uint4(lo.x, lo.y, hi.x, hi.y);
}
__device__ __forceinline__ void unpack8(uint4 r, float4& a, float4& b) {
    a = h2f4(make_uint2(r.x, r.y));
    b = h2f4(make_uint2(r.z, r.w));
}

// ---------------- prep: raw -> fp16 centered (ac) + fp16 1/sqrt(var box) --
// One wave per (z, 16-row seg), FULL 512-col row (8 cols/lane). 32 steps
// (rolled 4x8; t=31 harmless). Vertical-first mean: VA[col] slides over raw
// rows (subtract row re-loaded via 2-slack fifo); winC once per emit row.
__global__ __launch_bounds__(64, 2) void prep_f8(
    const float* __restrict__ outs, const float* __restrict__ labs,
    __half* __restrict__ ac, __half* __restrict__ rs, float* __restrict__ wsum)
{
    const int l = threadIdx.x;
    if (blockIdx.x == 0 && blockIdx.y == 0 && l < 24)
        wsum[l * 64] = 0.f;                   // zero per-z partial slots
    const int y0 = 16 * blockIdx.x;
    const int z  = blockIdx.y;

    const float* src = (z < 24) ? outs + z * HW : labs + (z - 24) * HW;
    __half* acd = ac + z * HW;
    __half* rsd = rs + z * HW;

    const int   col = 8 * l;
    const int   aL1 = ((l - 1) & 63) << 2;
    const int   aR1 = ((l + 1) & 63) << 2;
    const float lmE = (l > 0)  ? 1.f : 0.f;   // zero-pad left  edge
    const float rmE = (l < 63) ? 1.f : 0.f;   // zero-pad right edge

    // raw-row ring: slot t&7 holds row r=y0-7+t (written 2 steps ahead)
    float4 fA[8], fB[8];
    float4 foA[2], foB[2];                    // subtract row (r-8), 2-slack
    float4 gA[8], gB[8];                      // sq ring
    float4 VAa = {0,0,0,0}, VAb = {0,0,0,0};  // vertical raw sum (8 rows)
    float4 Vqa = {0,0,0,0}, Vqb = {0,0,0,0};  // vertical sq sum
    #pragma unroll
    for (int k = 0; k < 8; ++k) {
        gA[k] = make_float4(0,0,0,0); gB[k] = make_float4(0,0,0,0);
        fA[k] = make_float4(0,0,0,0); fB[k] = make_float4(0,0,0,0);
    }
    foA[0] = foA[1] = foB[0] = foB[1] = make_float4(0,0,0,0);
    {   // preload: slots read before first in-loop write
        const int pr[6] = { rcl(y0-7), rcl(y0-6), rcl(y0-11), rcl(y0-10),
                            rcl(y0-9), rcl(y0-8) };
        const int sl[6] = { 0, 1, 4, 5, 6, 7 };
        #pragma unroll
        for (int q = 0; q < 6; ++q) {
            fA[sl[q]] = *(const float4*)&src[pr[q] * WW + col];
            fB[sl[q]] = *(const float4*)&src[pr[q] * WW + col + 4];
        }
    }

    auto step = [&](const int t, const int kk) {
        const int   r  = y0 - 7 + t;
        const float rm = (r >= 0 && r < HH) ? 1.f : 0.f;
        // VA += raw(r)*rm - raw(r-8)*rm8
        {
            float4 ra = fA[kk], rb = fB[kk];
            VAa.x += ra.x*rm; VAa.y += ra.y*rm; VAa.z += ra.z*rm; VAa.w += ra.w*rm;
            VAb.x += rb.x*rm; VAb.y += rb.y*rm; VAb.z += rb.z*rm; VAb.w += rb.w*rm;
        }
        if (t >= 8) {
            const int   r8  = r - 8;
            const float rm8 = (r8 >= 0 && r8 < HH) ? 1.f : 0.f;
            float4 oa = foA[kk & 1], ob = foB[kk & 1];
            VAa.x -= oa.x*rm8; VAa.y -= oa.y*rm8; VAa.z -= oa.z*rm8; VAa.w -= oa.w*rm8;
            VAb.x -= ob.x*rm8; VAb.y -= ob.y*rm8; VAb.z -= ob.z*rm8; VAb.w -= ob.w*rm8;
        }
        if (t <= 28) {                        // prefetch row r+2 (2-slack)
            const int rn = rcl(r + 2);
            fA[(kk + 2) & 7] = *(const float4*)&src[rn * WW + col];
            fB[(kk + 2) & 7] = *(const float4*)&src[rn * WW + col + 4];
        }
        if (t >= 6 && t <= 28) {              // prefetch row r-6 (-> r-8 at t+2)
            const int ro = rcl(r - 6);
            foA[kk & 1] = *(const float4*)&src[ro * WW + col];
            foB[kk & 1] = *(const float4*)&src[ro * WW + col + 4];
        }
        if (t >= 8) {                         // ac at row c = r-4
            const int   c  = r - 4;
            const float cm = (c >= 0 && c < HH) ? 1.f : 0.f;
            // winC8 on VA: mean window sum (64 px)
            float p1 = VAa.x, p2 = p1+VAa.y, p3 = p2+VAa.z, p4 = p3+VAa.w;
            float p5 = p4+VAb.x, p6 = p5+VAb.y, p7 = p6+VAb.z, tt = p7+VAb.w;
            float s1 = VAb.w, s2 = VAb.z+s1, s3 = VAb.y+s2;
            float L1 = bpl(aL1, s1)*lmE, L2 = bpl(aL1, s2)*lmE, L3 = bpl(aL1, s3)*lmE;
            float R1 = bpl(aR1, p1)*rmE, R2 = bpl(aR1, p2)*rmE;
            float R3 = bpl(aR1, p3)*rmE, R4 = bpl(aR1, p4)*rmE;
            float4 rc0 = fA[(kk + 4) & 7], rc1 = fB[(kk + 4) & 7];  // raw row c
            float4 aL4, aH4;
            aL4.x = (rc0.x - (L3+p5)     * (1.f/64.f)) * cm;
            aL4.y = (rc0.y - (L2+p6)     * (1.f/64.f)) * cm;
            aL4.z = (rc0.z - (L1+p7)     * (1.f/64.f)) * cm;
            aL4.w = (rc0.w - tt          * (1.f/64.f)) * cm;
            aH4.x = (rc1.x - (tt-p1+R1)  * (1.f/64.f)) * cm;
            aH4.y = (rc1.y - (tt-p2+R2)  * (1.f/64.f)) * cm;
            aH4.z = (rc1.z - (tt-p3+R3)  * (1.f/64.f)) * cm;
            aH4.w = (rc1.w - (tt-p4+R4)  * (1.f/64.f)) * cm;
            if (t >= 11 && t <= 26)           // store own 16 rows
                *(uint4*)&acd[c * WW + col] = pack8(aL4, aH4);
            // Vq += sq - ring
            float4 qa = make_float4(aL4.x*aL4.x, aL4.y*aL4.y, aL4.z*aL4.z, aL4.w*aL4.w);
            float4 qb = make_float4(aH4.x*aH4.x, aH4.y*aH4.y, aH4.z*aH4.z, aH4.w*aH4.w);
            Vqa.x += qa.x - gA[kk].x; Vqa.y += qa.y - gA[kk].y;
            Vqa.z += qa.z - gA[kk].z; Vqa.w += qa.w - gA[kk].w;
            Vqb.x += qb.x - gB[kk].x; Vqb.y += qb.y - gB[kk].y;
            Vqb.z += qb.z - gB[kk].z; Vqb.w += qb.w - gB[kk].w;
            gA[kk] = qa; gB[kk] = qb;
            if (t >= 15 && t <= 30) {         // emit rs at row y = c-4
                const int y = c - 4;          // y in [y0, y0+15]
                float q1 = Vqa.x, q2 = q1+Vqa.y, q3 = q2+Vqa.z, q4 = q3+Vqa.w;
                float q5 = q4+Vqb.x, q6 = q5+Vqb.y, q7 = q6+Vqb.z, qt = q7+Vqb.w;
                float T1 = bpl(aR1, q1)*rmE, T2 = bpl(aR1, q2)*rmE;
                float T3 = bpl(aR1, q3)*rmE, T4 = bpl(aR1, q4)*rmE;
                float T5 = bpl(aR1, q5)*rmE, T6 = bpl(aR1, q6)*rmE;
                float T7 = bpl(aR1, q7)*rmE, Tg = bpl(aR1, qt)*rmE;
                float4 rL, rH;
                rL.x = fminf(__frsqrt_rn(fmaxf(qt-q1+T1, EPV)), 60000.f);
                rL.y = fminf(__frsqrt_rn(fmaxf(qt-q2+T2, EPV)), 60000.f);
                rL.z = fminf(__frsqrt_rn(fmaxf(qt-q3+T3, EPV)), 60000.f);
                rL.w = fminf(__frsqrt_rn(fmaxf(qt-q4+T4, EPV)), 60000.f);
                rH.x = fminf(__frsqrt_rn(fmaxf(qt-q5+T5, EPV)), 60000.f);
                rH.y = fminf(__frsqrt_rn(fmaxf(qt-q6+T6, EPV)), 60000.f);
                rH.z = fminf(__frsqrt_rn(fmaxf(qt-q7+T7, EPV)), 60000.f);
                rH.w = fminf(__frsqrt_rn(fmaxf(Tg,       EPV)), 60000.f);
                *(uint4*)&rsd[y * WW + col] = pack8(rL, rH);
            }
        }
    };
    for (int it = 0; it < 4; ++it) {
        const int t0 = it * 8;
        #pragma unroll
        for (int kk = 0; kk < 8; ++kk) step(t0 + kk, kk);
    }
}

// ---------------- main: product boxes, full-width rows, 4 j per wave ------
// One wave per (z, 8-row seg), 512 cols (8/lane). 16 steps (rolled 2x8;
// t=15 harmless). 1536 waves, XCD-chunked: XCD k owns z in {3k,3k+1,3k+2}.
__global__ __launch_bounds__(64, 2) void ncc_f8(
    const __half* __restrict__ ac, const __half* __restrict__ rs,
    float* __restrict__ wsum)
{
    const int l   = threadIdx.x;
    const int n   = blockIdx.x;            // 0..1535
    const int xcd = n & 7;
    const int p   = n >> 3;                // 0..191
    const int zq  = p >> 6;                // 0..2
    const int seg = p & 63;                // 0..63
    const int z   = 3 * xcd + zq;          // b*6 + i
    const int b   = z / 6;
    const int y0  = 8 * seg;

    const __half* acp = ac + z * HW;
    const __half* sip = rs + z * HW;
    const __half* bcp[4]; const __half* sjp[4];
    #pragma unroll
    for (int j = 0; j < 4; ++j) {
        bcp[j] = ac + (24 + b * 4 + j) * HW;
        sjp[j] = rs + (24 + b * 4 + j) * HW;
    }

    const int   col = 8 * l;
    const int   aR1 = ((l + 1) & 63) << 2;
    const float rmE = (l < 63) ? 1.f : 0.f;

    uint4 fa[2], fb[4][2];      // add rows    (2-step slack), raw fp16
    uint4 faO[2], fbO[4][2];    // subtract rows (2-step slack)
    {
        const int r0 = rcl(y0 - 3), r1 = rcl(y0 - 2);
        fa[0] = *(const uint4*)&acp[r0 * WW + col];
        fa[1] = *(const uint4*)&acp[r1 * WW + col];
        faO[0] = fa[0]; faO[1] = fa[1];
        #pragma unroll
        for (int j = 0; j < 4; ++j) {
            fb[j][0] = *(const uint4*)&bcp[j][r0 * WW + col];
            fb[j][1] = *(const uint4*)&bcp[j][r1 * WW + col];
            fbO[j][0] = fb[j][0]; fbO[j][1] = fb[j][1];
        }
    }

    float4 VpL[4], VpH[4];
    uint4 psiB[2], psjB[2][4];
    float4 xsL = make_float4(0,0,0,0), xsH = make_float4(0,0,0,0);
    #pragma unroll
    for (int j = 0; j < 4; ++j) {
        VpL[j] = make_float4(0,0,0,0); VpH[j] = make_float4(0,0,0,0);
        psjB[0][j] = make_uint4(0,0,0,0); psjB[1][j] = make_uint4(0,0,0,0);
    }
    psiB[0] = make_uint4(0,0,0,0); psiB[1] = make_uint4(0,0,0,0);

    auto step = [&](const int t, const int kk) {
        const int   c  = y0 - 3 + t;                 // row being ADDED
        const float rm = (c >= 0 && c < HH) ? 1.f : 0.f;
        uint4 ar = fa[kk & 1];
        uint4 br0 = fb[0][kk & 1], br1 = fb[1][kk & 1];
        uint4 br2 = fb[2][kk & 1], br3 = fb[3][kk & 1];
        uint4 arO = faO[kk & 1];
        uint4 bo0 = fbO[0][kk & 1], bo1 = fbO[1][kk & 1];
        uint4 bo2 = fbO[2][kk & 1], bo3 = fbO[3][kk & 1];
        if (t <= 12) {                               // add-row prefetch
            const int rn = rcl(c + 2);
            fa[kk & 1] = *(const uint4*)&acp[rn * WW + col];
            #pragma unroll
            for (int j = 0; j < 4; ++j)
                fb[j][kk & 1] = *(const uint4*)&bcp[j][rn * WW + col];
        }
        if (t >= 6 && t <= 12) {                     // subtract-row prefetch
            const int ro = rcl(c - 6);               // used at t+2 (row c-8)
            faO[kk & 1] = *(const uint4*)&acp[ro * WW + col];
            #pragma unroll
            for (int j = 0; j < 4; ++j)
                fbO[j][kk & 1] = *(const uint4*)&bcp[j][ro * WW + col];
        }
        // add products of row c
        {
            float4 avL, avH; unpack8(ar, avL, avH);
            avL.x *= rm; avL.y *= rm; avL.z *= rm; avL.w *= rm;
            avH.x *= rm; avH.y *= rm; avH.z *= rm; avH.w *= rm;
            float4 bL, bH;
            unpack8(br0, bL, bH);
            VpL[0].x += avL.x*bL.x; VpL[0].y += avL.y*bL.y; VpL[0].z += avL.z*bL.z; VpL[0].w += avL.w*bL.w;
            VpH[0].x += avH.x*bH.x; VpH[0].y += avH.y*bH.y; VpH[0].z += avH.z*bH.z; VpH[0].w += avH.w*bH.w;
            unpack8(br1, bL, bH);
            VpL[1].x += avL.x*bL.x; VpL[1].y += avL.y*bL.y; VpL[1].z += avL.z*bL.z; VpL[1].w += avL.w*bL.w;
            VpH[1].x += avH.x*bH.x; VpH[1].y += avH.y*bH.y; VpH[1].z += avH.z*bH.z; VpH[1].w += avH.w*bH.w;
            unpack8(br2, bL, bH);
            VpL[2].x += avL.x*bL.x; VpL[2].y += avL.y*bL.y; VpL[2].z += avL.z*bL.z; VpL[2].w += avL.w*bL.w;
            VpH[2].x += avH.x*bH.x; VpH[2].y += avH.y*bH.y; VpH[2].z += avH.z*bH.z; VpH[2].w += avH.w*bH.w;
            unpack8(br3, bL, bH);
            VpL[3].x += avL.x*bL.x; VpL[3].y += avL.y*bL.y; VpL[3].z += avL.z*bL.z; VpL[3].w += avL.w*bL.w;
            VpH[3].x += avH.x*bH.x; VpH[3].y += avH.y*bH.y; VpH[3].z += avH.z*bH.z; VpH[3].w += avH.w*bH.w;
        }
        // subtract products of row c-8
        if (t >= 8) {
            const float rmO = ((c - 8) >= 0) ? 1.f : 0.f;
            float4 avL, avH; unpack8(arO, avL, avH);
            avL.x *= rmO; avL.y *= rmO; avL.z *= rmO; avL.w *= rmO;
            avH.x *= rmO; avH.y *= rmO; avH.z *= rmO; avH.w *= rmO;
            float4 bL, bH;
            unpack8(bo0, bL, bH);
            VpL[0].x -= avL.x*bL.x; VpL[0].y -= avL.y*bL.y; VpL[0].z -= avL.z*bL.z; VpL[0].w -= avL.w*bL.w;
            VpH[0].x -= avH.x*bH.x; VpH[0].y -= avH.y*bH.y; VpH[0].z -= avH.z*bH.z; VpH[0].w -= avH.w*bH.w;
            unpack8(bo1, bL, bH);
            VpL[1].x -= avL.x*bL.x; VpL[1].y -= avL.y*bL.y; VpL[1].z -= avL.z*bL.z; VpL[1].w -= avL.w*bL.w;
            VpH[1].x -= avH.x*bH.x; VpH[1].y -= avH.y*bH.y; VpH[1].z -= avH.z*bH.z; VpH[1].w -= avH.w*bH.w;
            unpack8(bo2, bL, bH);
            VpL[2].x -= avL.x*bL.x; VpL[2].y -= avL.y*bL.y; VpL[2].z -= avL.z*bL.z; VpL[2].w -= avL.w*bL.w;
            VpH[2].x -= avH.x*bH.x; VpH[2].y -= avH.y*bH.y; VpH[2].z -= avH.z*bH.z; VpH[2].w -= avH.w*bH.w;
            unpack8(bo3, bL, bH);
            VpL[3].x -= avL.x*bL.x; VpL[3].y -= avL.y*bL.y; VpL[3].z -= avL.z*bL.z; VpL[3].w -= avL.w*bL.w;
            VpH[3].x -= avH.x*bH.x; VpH[3].y -= avH.y*bH.y; VpH[3].z -= avH.z*bH.z; VpH[3].w -= avH.w*bH.w;
        }
        // emit row y = y0+t-7 (psi/psj loaded 2 steps ago)
        if (t >= 7 && t <= 14) {
            float4 pL, pH; unpack8(psiB[t & 1], pL, pH);
            float4 mmL = make_float4(-1,-1,-1,-1), mmH = make_float4(-1,-1,-1,-1);
            #pragma unroll
            for (int j = 0; j < 4; ++j) {
                float p1 = VpL[j].x, p2 = p1+VpL[j].y, p3 = p2+VpL[j].z, p4 = p3+VpL[j].w;
                float p5 = p4+VpH[j].x, p6 = p5+VpH[j].y, p7 = p6+VpH[j].z, tt = p7+VpH[j].w;
                float R1 = bpl(aR1, p1)*rmE, R2 = bpl(aR1, p2)*rmE;
                float R3 = bpl(aR1, p3)*rmE, R4 = bpl(aR1, p4)*rmE;
                float R5 = bpl(aR1, p5)*rmE, R6 = bpl(aR1, p6)*rmE;
                float R7 = bpl(aR1, p7)*rmE, Rg = bpl(aR1, tt)*rmE;
                float4 sL, sH; unpack8(psjB[t & 1][j], sL, sH);
                mmL.x = fmaxf(mmL.x, (tt-p1+R1) * (pL.x*sL.x));
                mmL.y = fmaxf(mmL.y, (tt-p2+R2) * (pL.y*sL.y));
                mmL.z = fmaxf(mmL.z, (tt-p3+R3) * (pL.z*sL.z));
                mmL.w = fmaxf(mmL.w, (tt-p4+R4) * (pL.w*sL.w));
                mmH.x = fmaxf(mmH.x, (tt-p5+R5) * (pH.x*sH.x));
                mmH.y = fmaxf(mmH.y, (tt-p6+R6) * (pH.y*sH.y));
                mmH.z = fmaxf(mmH.z, (tt-p7+R7) * (pH.z*sH.z));
                mmH.w = fmaxf(mmH.w, Rg         * (pH.w*sH.w));
            }
            xsL.x += 1.f - fminf(mmL.x, 1.f);
            xsL.y += 1.f - fminf(mmL.y, 1.f);
            xsL.z += 1.f - fminf(mmL.z, 1.f);
            xsL.w += 1.f - fminf(mmL.w, 1.f);
            xsH.x += 1.f - fminf(mmH.x, 1.f);
            xsH.y += 1.f - fminf(mmH.y, 1.f);
            xsH.z += 1.f - fminf(mmH.z, 1.f);
            xsH.w += 1.f - fminf(mmH.w, 1.f);
        }
        if (t >= 5 && t <= 12) {             // denom prefetch, 2-step slack
            const int yn = min(y0 + t - 5, HH - 1);
            psiB[t & 1] = *(const uint4*)&sip[yn * WW + col];
            #pragma unroll
            for (int j = 0; j < 4; ++j)
                psjB[t & 1][j] = *(const uint4*)&sjp[j][yn * WW + col];
        }
    };
    for (int it = 0; it < 2; ++it) {
        const int t0 = it * 8;
        #pragma unroll
        for (int kk = 0; kk < 8; ++kk) step(t0 + kk, kk);
    }

    float xt = xsL.x + xsL.y + xsL.z + xsL.w + xsH.x + xsH.y + xsH.z + xsH.w;
    #pragma unroll
    for (int off = 32; off > 0; off >>= 1) xt += __shfl_down(xt, off);
    if (l == 0) atomicAdd(&wsum[z * 64], xt);   // per-z line, 64-way only
}

// ---------------- finalize: 24 partials -> 25 outputs ---------------------
__global__ void fin_f4(const float* __restrict__ wsum, float* __restrict__ out)
{
    const int l = threadIdx.x;
    float v = (l < 24) ? wsum[l * 64] : 0.f;
    if (l < 24) out[1 + l] = v * (1.f / (float)HW);
    #pragma unroll
    for (int off = 32; off > 0; off >>= 1) v += __shfl_down(v, off);
    if (l == 0) out[0] = v * (1.f / (24.f * (float)HW));
}

extern "C" void kernel_launch(void* const* d_in, const int* in_sizes, int n_in,
                              void* d_out, int out_size, void* d_ws, size_t ws_size,
                              hipStream_t stream) {
    const float* outs = (const float*)d_in[0];   // (4,6,512,512)
    const float* labs = (const float*)d_in[1];   // (4,4,512,512)
    float* out = (float*)d_out;                  // 25 floats
    float* ws  = (float*)d_ws;

    __half* acw  = (__half*)ws;            // 40*HW halves (a:0..23, b:24..39)
    __half* rsw  = (__half*)ws + 40 * HW;  // 40*HW halves (fp16 1/sqrt(var))
    float*  wsum = ws + 40 * HW;           // floats: after the two half arrays

    // prep: 32 segs(16 rows) x 40 images, full-width waves (also zeroes wsum)
    prep_f8<<<dim3(32, 40), 64, 0, stream>>>(outs, labs, acw, rsw, wsum);
    // main: 1536 blocks (24 z x 64 segs of 8 rows), XCD-chunked decode
    ncc_f8<<<dim3(1536, 1, 1), 64, 0, stream>>>(acw, rsw, wsum);
    // finalize: one wave
    fin_f4<<<dim3(1, 1, 1), 64, 0, stream>>>(wsum, out);
}

// Round 9
// 131.755 us; speedup vs baseline: 1.1673x; 1.1673x over previous
//
#include <hip/hip_runtime.h>
#include <hip/hip_fp16.h>

#define HH 512
#define WW 512
#define HW (HH*WW)
#define EPV 1e-20f

// R18: 8 cols/lane with CENTERED windows (R17 had a +4 column shift in the
// rs/ncc windows -- right-leaning formulas kept after dropping the -4 col
// frame; absmax 0.0039 = edge-area signature). Window W(x)=sum cols x-3..x+4
// via 3 left-suffix + 4 right-prefix bpermutes (7 bp / 8 cols, the verified
// ac-window pattern). Spill fix: R17 ncc_f8 spilled (VGPR 128 < ~190 live,
// WRITE_SIZE 80MB = scratch) because launch_bounds(64,2) is only a floor;
// amdgpu_waves_per_eu(min,max) pins the allocator budget. ncc state trimmed
// to ~140 (1-slack subtract reload, exact fp16 telescoping); prep uses three
// 2-slack raw fifos + a packed-fp16 ac ring (32 regs) instead of fp32 rings,
// adds ALSO use packed values so the variance slide telescopes exactly.
// Keeps: fp16 intermediates, XCD-chunked ncc, per-z wsum + fin, barrier-free.

__device__ __forceinline__ float bpl(int addr, float v) {
    return __int_as_float(__builtin_amdgcn_ds_bpermute(addr, __float_as_int(v)));
}
__device__ __forceinline__ int rcl(int r) { return min(max(r, 0), HH - 1); }

__device__ __forceinline__ float4 h2f4(uint2 r) {
    __half2 lo = *(__half2*)&r.x, hi = *(__half2*)&r.y;
    float2 a = __half22float2(lo), b = __half22float2(hi);
    return make_float4(a.x, a.y, b.x, b.y);
}
__device__ __forceinline__ uint2 f2h4(float4 v) {
    __half2 lo = __floats2half2_rn(v.x, v.y);
    __half2 hi = __floats2half2_rn(v.z, v.w);
    uint2 r;
    r.x = *(unsigned int*)&lo;
    r.y = *(unsigned int*)&hi;
    return r;
}
__device__ __forceinline__ uint4 pack8(float4 a, float4 b) {
    uint2 lo = f2h4(a), hi = f2h4(b);
    return make_uint4(lo.x, lo.y, hi.x, hi.y);
}
__device__ __forceinline__ void unpack8(uint4 r, float4& a, float4& b) {
    a = h2f4(make_uint2(r.x, r.y));
    b = h2f4(make_uint2(r.z, r.w));
}

// ---------------- prep: raw -> fp16 centered (ac) + fp16 1/sqrt(var box) --
// One wave per (z, 8-row seg), full 512-col rows. 23 steps.
// r = y0-7+t (VA add row), c = r-4 (ac row), y = c-4 (rs row).
__global__ void __launch_bounds__(64)
__attribute__((amdgpu_waves_per_eu(3, 3)))
prep_f8(const float* __restrict__ outs, const float* __restrict__ labs,
        __half* __restrict__ ac, __half* __restrict__ rs,
        float* __restrict__ wsum)
{
    const int l = threadIdx.x;
    if (blockIdx.x == 0 && blockIdx.y == 0 && l < 24)
        wsum[l * 64] = 0.f;                   // zero per-z partial slots
    const int y0 = 8 * blockIdx.x;
    const int z  = blockIdx.y;

    const float* src = (z < 24) ? outs + z * HW : labs + (z - 24) * HW;
    __half* acd = ac + z * HW;
    __half* rsd = rs + z * HW;

    const int   col = 8 * l;
    const int   aL1 = ((l - 1) & 63) << 2;
    const int   aR1 = ((l + 1) & 63) << 2;
    const float lmE = (l > 0)  ? 1.f : 0.f;
    const float rmE = (l < 63) ? 1.f : 0.f;

    float4 fNA[2], fNB[2];   // add row r        (2-slack)
    float4 fOA[2], fOB[2];   // subtract row r-8 (2-slack)
    float4 fCA[2], fCB[2];   // center row c     (2-slack)
    uint4  pk[8];            // packed-fp16 ac ring (variance subtract)
    float4 VAa = {0,0,0,0}, VAb = {0,0,0,0};
    float4 Vqa = {0,0,0,0}, Vqb = {0,0,0,0};
    #pragma unroll
    for (int k = 0; k < 8; ++k) pk[k] = make_uint4(0,0,0,0);
    #pragma unroll
    for (int k = 0; k < 2; ++k) {
        fOA[k] = make_float4(0,0,0,0); fOB[k] = make_float4(0,0,0,0);
        fCA[k] = make_float4(0,0,0,0); fCB[k] = make_float4(0,0,0,0);
    }
    fNA[0] = *(const float4*)&src[rcl(y0 - 7) * WW + col];
    fNB[0] = *(const float4*)&src[rcl(y0 - 7) * WW + col + 4];
    fNA[1] = *(const float4*)&src[rcl(y0 - 6) * WW + col];
    fNB[1] = *(const float4*)&src[rcl(y0 - 6) * WW + col + 4];

    auto step = [&](const int t) {
        const int   r  = y0 - 7 + t;
        const float rm = (r >= 0 && r < HH) ? 1.f : 0.f;
        {   // VA += raw(r)
            float4 ra = fNA[t & 1], rb = fNB[t & 1];
            VAa.x += ra.x*rm; VAa.y += ra.y*rm; VAa.z += ra.z*rm; VAa.w += ra.w*rm;
            VAb.x += rb.x*rm; VAb.y += rb.y*rm; VAb.z += rb.z*rm; VAb.w += rb.w*rm;
        }
        if (t >= 8) {   // VA -= raw(r-8)
            const float rm8 = ((r - 8) >= 0 && (r - 8) < HH) ? 1.f : 0.f;
            float4 oa = fOA[t & 1], ob = fOB[t & 1];
            VAa.x -= oa.x*rm8; VAa.y -= oa.y*rm8; VAa.z -= oa.z*rm8; VAa.w -= oa.w*rm8;
            VAb.x -= ob.x*rm8; VAb.y -= ob.y*rm8; VAb.z -= ob.z*rm8; VAb.w -= ob.w*rm8;
        }
        if (t <= 20) {                        // prefetch add row r+2
            const int rn = rcl(r + 2);
            fNA[t & 1] = *(const float4*)&src[rn * WW + col];
            fNB[t & 1] = *(const float4*)&src[rn * WW + col + 4];
        }
        if (t >= 6 && t <= 20) {              // prefetch subtract row (r+2)-8
            const int ro = rcl(r - 6);
            fOA[t & 1] = *(const float4*)&src[ro * WW + col];
            fOB[t & 1] = *(const float4*)&src[ro * WW + col + 4];
        }
        if (t >= 6 && t <= 20) {              // prefetch center row c+2 = r-2
            const int rc = rcl(r - 2);
            fCA[t & 1] = *(const float4*)&src[rc * WW + col];
            fCB[t & 1] = *(const float4*)&src[rc * WW + col + 4];
        }
        if (t >= 8) {
            const int   c  = r - 4;
            const float cm = (c >= 0 && c < HH) ? 1.f : 0.f;
            // centered 8-wide window on VA (mean box, 64 px)
            float p1 = VAa.x, p2 = p1+VAa.y, p3 = p2+VAa.z, p4 = p3+VAa.w;
            float p5 = p4+VAb.x, p6 = p5+VAb.y, p7 = p6+VAb.z, tt = p7+VAb.w;
            float s1 = VAb.w, s2 = VAb.z+s1, s3 = VAb.y+s2;
            float L1 = bpl(aL1, s1)*lmE, L2 = bpl(aL1, s2)*lmE, L3 = bpl(aL1, s3)*lmE;
            float R1 = bpl(aR1, p1)*rmE, R2 = bpl(aR1, p2)*rmE;
            float R3 = bpl(aR1, p3)*rmE, R4 = bpl(aR1, p4)*rmE;
            float4 rc0 = fCA[t & 1], rc1 = fCB[t & 1];     // raw row c
            float4 aL4, aH4;
            aL4.x = (rc0.x - (L3+p5)    * (1.f/64.f)) * cm;
            aL4.y = (rc0.y - (L2+p6)    * (1.f/64.f)) * cm;
            aL4.z = (rc0.z - (L1+p7)    * (1.f/64.f)) * cm;
            aL4.w = (rc0.w - tt         * (1.f/64.f)) * cm;
            aH4.x = (rc1.x - (tt-p1+R1) * (1.f/64.f)) * cm;
            aH4.y = (rc1.y - (tt-p2+R2) * (1.f/64.f)) * cm;
            aH4.z = (rc1.z - (tt-p3+R3) * (1.f/64.f)) * cm;
            aH4.w = (rc1.w - (tt-p4+R4) * (1.f/64.f)) * cm;
            uint4 pkNew = pack8(aL4, aH4);
            if (t >= 11 && t <= 18)           // store own 8 rows
                *(uint4*)&acd[c * WW + col] = pkNew;
            // variance slide on the ROUNDED values (exact telescoping)
            float4 qnL, qnH; unpack8(pkNew, qnL, qnH);
            Vqa.x += qnL.x*qnL.x; Vqa.y += qnL.y*qnL.y;
            Vqa.z += qnL.z*qnL.z; Vqa.w += qnL.w*qnL.w;
            Vqb.x += qnH.x*qnH.x; Vqb.y += qnH.y*qnH.y;
            Vqb.z += qnH.z*qnH.z; Vqb.w += qnH.w*qnH.w;
            if (t >= 16) {                    // subtract sq(ac(c-8))
                float4 oL, oH; unpack8(pk[t & 7], oL, oH);
                Vqa.x -= oL.x*oL.x; Vqa.y -= oL.y*oL.y;
                Vqa.z -= oL.z*oL.z; Vqa.w -= oL.w*oL.w;
                Vqb.x -= oH.x*oH.x; Vqb.y -= oH.y*oH.y;
                Vqb.z -= oH.z*oH.z; Vqb.w -= oH.w*oH.w;
            }
            pk[t & 7] = pkNew;
            if (t >= 15 && t <= 22) {         // emit rs at row y = c-4
                const int y = c - 4;          // y in [y0, y0+7]
                float q1 = Vqa.x, q2 = q1+Vqa.y, q3 = q2+Vqa.z, q4 = q3+Vqa.w;
                float q5 = q4+Vqb.x, q6 = q5+Vqb.y, q7 = q6+Vqb.z, qt = q7+Vqb.w;
                float z1 = Vqb.w, z2 = Vqb.z+z1, z3 = Vqb.y+z2;
                float Lq1 = bpl(aL1, z1)*lmE, Lq2 = bpl(aL1, z2)*lmE, Lq3 = bpl(aL1, z3)*lmE;
                float Rq1 = bpl(aR1, q1)*rmE, Rq2 = bpl(aR1, q2)*rmE;
                float Rq3 = bpl(aR1, q3)*rmE, Rq4 = bpl(aR1, q4)*rmE;
                float4 rL, rH;
                rL.x = fminf(__frsqrt_rn(fmaxf(Lq3+q5,    EPV)), 60000.f);
                rL.y = fminf(__frsqrt_rn(fmaxf(Lq2+q6,    EPV)), 60000.f);
                rL.z = fminf(__frsqrt_rn(fmaxf(Lq1+q7,    EPV)), 60000.f);
                rL.w = fminf(__frsqrt_rn(fmaxf(qt,        EPV)), 60000.f);
                rH.x = fminf(__frsqrt_rn(fmaxf(qt-q1+Rq1, EPV)), 60000.f);
                rH.y = fminf(__frsqrt_rn(fmaxf(qt-q2+Rq2, EPV)), 60000.f);
                rH.z = fminf(__frsqrt_rn(fmaxf(qt-q3+Rq3, EPV)), 60000.f);
                rH.w = fminf(__frsqrt_rn(fmaxf(qt-q4+Rq4, EPV)), 60000.f);
                *(uint4*)&rsd[y * WW + col] = pack8(rL, rH);
            }
        }
    };
    #pragma unroll
    for (int t = 0; t < 23; ++t) step(t);
}

// ---------------- main: product boxes, full-width rows, 4 j per wave ------
// One wave per (z, 8-row seg). 15 steps. 1536 waves, XCD-chunked.
// Vp[j] += p(row c) - p(row c-8); subtract rows via 1-slack reload (exact
// fp16 telescoping). Emit window centered (7 bp / 8 cols / j).
__global__ void __launch_bounds__(64)
__attribute__((amdgpu_waves_per_eu(2, 2)))
ncc_f8(const __half* __restrict__ ac, const __half* __restrict__ rs,
       float* __restrict__ wsum)
{
    const int l   = threadIdx.x;
    const int n   = blockIdx.x;            // 0..1535
    const int xcd = n & 7;
    const int p   = n >> 3;                // 0..191
    const int zq  = p >> 6;                // 0..2
    const int seg = p & 63;                // 0..63
    const int z   = 3 * xcd + zq;          // b*6 + i
    const int b   = z / 6;
    const int y0  = 8 * seg;

    const __half* acp = ac + z * HW;
    const __half* sip = rs + z * HW;
    const __half* bcp[4]; const __half* sjp[4];
    #pragma unroll
    for (int j = 0; j < 4; ++j) {
        bcp[j] = ac + (24 + b * 4 + j) * HW;
        sjp[j] = rs + (24 + b * 4 + j) * HW;
    }

    const int   col = 8 * l;
    const int   aL1 = ((l - 1) & 63) << 2;
    const int   aR1 = ((l + 1) & 63) << 2;
    const float lmE = (l > 0)  ? 1.f : 0.f;
    const float rmE = (l < 63) ? 1.f : 0.f;

    uint4 fa[2], fb[4][2];                 // add rows (2-slack)
    uint4 oA, oB[4];                       // subtract row (1-slack)
    {
        const int r0 = rcl(y0 - 3), r1 = rcl(y0 - 2);
        fa[0] = *(const uint4*)&acp[r0 * WW + col];
        fa[1] = *(const uint4*)&acp[r1 * WW + col];
        #pragma unroll
        for (int j = 0; j < 4; ++j) {
            fb[j][0] = *(const uint4*)&bcp[j][r0 * WW + col];
            fb[j][1] = *(const uint4*)&bcp[j][r1 * WW + col];
            oB[j] = make_uint4(0,0,0,0);
        }
        oA = make_uint4(0,0,0,0);
    }

    float4 VpL[4], VpH[4];
    uint4 psiB[2], psjB[2][4];
    float4 xsL = make_float4(0,0,0,0), xsH = make_float4(0,0,0,0);
    #pragma unroll
    for (int j = 0; j < 4; ++j) {
        VpL[j] = make_float4(0,0,0,0); VpH[j] = make_float4(0,0,0,0);
        psjB[0][j] = make_uint4(0,0,0,0); psjB[1][j] = make_uint4(0,0,0,0);
    }
    psiB[0] = make_uint4(0,0,0,0); psiB[1] = make_uint4(0,0,0,0);

    auto step = [&](const int t) {
        const int   c  = y0 - 3 + t;                 // row being ADDED
        const float rm = (c >= 0 && c < HH) ? 1.f : 0.f;
        uint4 ar = fa[t & 1];
        uint4 br0 = fb[0][t & 1], br1 = fb[1][t & 1];
        uint4 br2 = fb[2][t & 1], br3 = fb[3][t & 1];
        uint4 arO = oA;                              // row c-8 (valid t>=8)
        uint4 bo0 = oB[0], bo1 = oB[1], bo2 = oB[2], bo3 = oB[3];
        if (t <= 12) {                               // add-row prefetch
            const int rn = rcl(c + 2);
            fa[t & 1] = *(const uint4*)&acp[rn * WW + col];
            #pragma unroll
            for (int j = 0; j < 4; ++j)
                fb[j][t & 1] = *(const uint4*)&bcp[j][rn * WW + col];
        }
        if (t >= 7 && t <= 13) {                     // subtract-row prefetch
            const int ro = rcl(c - 7);               // used next step (c'-8)
            oA = *(const uint4*)&acp[ro * WW + col];
            #pragma unroll
            for (int j = 0; j < 4; ++j)
                oB[j] = *(const uint4*)&bcp[j][ro * WW + col];
        }
        {   // add products of row c
            float4 avL, avH; unpack8(ar, avL, avH);
            avL.x *= rm; avL.y *= rm; avL.z *= rm; avL.w *= rm;
            avH.x *= rm; avH.y *= rm; avH.z *= rm; avH.w *= rm;
            float4 bL, bH;
            unpack8(br0, bL, bH);
            VpL[0].x += avL.x*bL.x; VpL[0].y += avL.y*bL.y; VpL[0].z += avL.z*bL.z; VpL[0].w += avL.w*bL.w;
            VpH[0].x += avH.x*bH.x; VpH[0].y += avH.y*bH.y; VpH[0].z += avH.z*bH.z; VpH[0].w += avH.w*bH.w;
            unpack8(br1, bL, bH);
            VpL[1].x += avL.x*bL.x; VpL[1].y += avL.y*bL.y; VpL[1].z += avL.z*bL.z; VpL[1].w += avL.w*bL.w;
            VpH[1].x += avH.x*bH.x; VpH[1].y += avH.y*bH.y; VpH[1].z += avH.z*bH.z; VpH[1].w += avH.w*bH.w;
            unpack8(br2, bL, bH);
            VpL[2].x += avL.x*bL.x; VpL[2].y += avL.y*bL.y; VpL[2].z += avL.z*bL.z; VpL[2].w += avL.w*bL.w;
            VpH[2].x += avH.x*bH.x; VpH[2].y += avH.y*bH.y; VpH[2].z += avH.z*bH.z; VpH[2].w += avH.w*bH.w;
            unpack8(br3, bL, bH);
            VpL[3].x += avL.x*bL.x; VpL[3].y += avL.y*bL.y; VpL[3].z += avL.z*bL.z; VpL[3].w += avL.w*bL.w;
            VpH[3].x += avH.x*bH.x; VpH[3].y += avH.y*bH.y; VpH[3].z += avH.z*bH.z; VpH[3].w += avH.w*bH.w;
        }
        if (t >= 8) {   // subtract products of row c-8
            const float rmO = ((c - 8) >= 0) ? 1.f : 0.f;
            float4 avL, avH; unpack8(arO, avL, avH);
            avL.x *= rmO; avL.y *= rmO; avL.z *= rmO; avL.w *= rmO;
            avH.x *= rmO; avH.y *= rmO; avH.z *= rmO; avH.w *= rmO;
            float4 bL, bH;
            unpack8(bo0, bL, bH);
            VpL[0].x -= avL.x*bL.x; VpL[0].y -= avL.y*bL.y; VpL[0].z -= avL.z*bL.z; VpL[0].w -= avL.w*bL.w;
            VpH[0].x -= avH.x*bH.x; VpH[0].y -= avH.y*bH.y; VpH[0].z -= avH.z*bH.z; VpH[0].w -= avH.w*bH.w;
            unpack8(bo1, bL, bH);
            VpL[1].x -= avL.x*bL.x; VpL[1].y -= avL.y*bL.y; VpL[1].z -= avL.z*bL.z; VpL[1].w -= avL.w*bL.w;
            VpH[1].x -= avH.x*bH.x; VpH[1].y -= avH.y*bH.y; VpH[1].z -= avH.z*bH.z; VpH[1].w -= avH.w*bH.w;
            unpack8(bo2, bL, bH);
            VpL[2].x -= avL.x*bL.x; VpL[2].y -= avL.y*bL.y; VpL[2].z -= avL.z*bL.z; VpL[2].w -= avL.w*bL.w;
            VpH[2].x -= avH.x*bH.x; VpH[2].y -= avH.y*bH.y; VpH[2].z -= avH.z*bH.z; VpH[2].w -= avH.w*bH.w;
            unpack8(bo3, bL, bH);
            VpL[3].x -= avL.x*bL.x; VpL[3].y -= avL.y*bL.y; VpL[3].z -= avL.z*bL.z; VpL[3].w -= avL.w*bL.w;
            VpH[3].x -= avH.x*bH.x; VpH[3].y -= avH.y*bH.y; VpH[3].z -= avH.z*bH.z; VpH[3].w -= avH.w*bH.w;
        }
        if (t >= 7 && t <= 14) {   // emit row y = y0+t-7 (all cols valid)
            float4 pL, pH; unpack8(psiB[t & 1], pL, pH);
            float4 mmL = make_float4(-1,-1,-1,-1), mmH = make_float4(-1,-1,-1,-1);
            #pragma unroll
            for (int j = 0; j < 4; ++j) {
                float q1 = VpL[j].x, q2 = q1+VpL[j].y, q3 = q2+VpL[j].z, q4 = q3+VpL[j].w;
                float q5 = q4+VpH[j].x, q6 = q5+VpH[j].y, q7 = q6+VpH[j].z, q8 = q7+VpH[j].w;
                float s1 = VpH[j].w, s2 = VpH[j].z+s1, s3 = VpH[j].y+s2;
                float L1 = bpl(aL1, s1)*lmE, L2 = bpl(aL1, s2)*lmE, L3 = bpl(aL1, s3)*lmE;
                float R1 = bpl(aR1, q1)*rmE, R2 = bpl(aR1, q2)*rmE;
                float R3 = bpl(aR1, q3)*rmE, R4 = bpl(aR1, q4)*rmE;
                float4 sL, sH; unpack8(psjB[t & 1][j], sL, sH);
                mmL.x = fmaxf(mmL.x, (L3+q5)    * (pL.x*sL.x));
                mmL.y = fmaxf(mmL.y, (L2+q6)    * (pL.y*sL.y));
                mmL.z = fmaxf(mmL.z, (L1+q7)    * (pL.z*sL.z));
                mmL.w = fmaxf(mmL.w, q8         * (pL.w*sL.w));
                mmH.x = fmaxf(mmH.x, (q8-q1+R1) * (pH.x*sH.x));
                mmH.y = fmaxf(mmH.y, (q8-q2+R2) * (pH.y*sH.y));
                mmH.z = fmaxf(mmH.z, (q8-q3+R3) * (pH.z*sH.z));
                mmH.w = fmaxf(mmH.w, (q8-q4+R4) * (pH.w*sH.w));
            }
            xsL.x += 1.f - fminf(mmL.x, 1.f);
            xsL.y += 1.f - fminf(mmL.y, 1.f);
            xsL.z += 1.f - fminf(mmL.z, 1.f);
            xsL.w += 1.f - fminf(mmL.w, 1.f);
            xsH.x += 1.f - fminf(mmH.x, 1.f);
            xsH.y += 1.f - fminf(mmH.y, 1.f);
            xsH.z += 1.f - fminf(mmH.z, 1.f);
            xsH.w += 1.f - fminf(mmH.w, 1.f);
        }
        if (t >= 5 && t <= 12) {   // denom prefetch, 2-step slack
            const int yn = min(y0 + t - 5, HH - 1);
            psiB[t & 1] = *(const uint4*)&sip[yn * WW + col];
            #pragma unroll
            for (int j = 0; j < 4; ++j)
                psjB[t & 1][j] = *(const uint4*)&sjp[j][yn * WW + col];
        }
    };
    #pragma unroll
    for (int t = 0; t < 15; ++t) step(t);

    float xt = xsL.x + xsL.y + xsL.z + xsL.w + xsH.x + xsH.y + xsH.z + xsH.w;
    #pragma unroll
    for (int off = 32; off > 0; off >>= 1) xt += __shfl_down(xt, off);
    if (l == 0) atomicAdd(&wsum[z * 64], xt);
}

// ---------------- finalize: 24 partials -> 25 outputs ---------------------
__global__ void fin_f4(const float* __restrict__ wsum, float* __restrict__ out)
{
    const int l = threadIdx.x;
    float v = (l < 24) ? wsum[l * 64] : 0.f;
    if (l < 24) out[1 + l] = v * (1.f / (float)HW);
    #pragma unroll
    for (int off = 32; off > 0; off >>= 1) v += __shfl_down(v, off);
    if (l == 0) out[0] = v * (1.f / (24.f * (float)HW));
}

extern "C" void kernel_launch(void* const* d_in, const int* in_sizes, int n_in,
                              void* d_out, int out_size, void* d_ws, size_t ws_size,
                              hipStream_t stream) {
    const float* outs = (const float*)d_in[0];   // (4,6,512,512)
    const float* labs = (const float*)d_in[1];   // (4,4,512,512)
    float* out = (float*)d_out;                  // 25 floats
    float* ws  = (float*)d_ws;

    __half* acw  = (__half*)ws;            // 40*HW halves (a:0..23, b:24..39)
    __half* rsw  = (__half*)ws + 40 * HW;  // 40*HW halves (fp16 1/sqrt(var))
    float*  wsum = ws + 40 * HW;           // floats: after the two half arrays

    // prep: 64 segs(8 rows) x 40 images, full-width waves (also zeroes wsum)
    prep_f8<<<dim3(64, 40), 64, 0, stream>>>(outs, labs, acw, rsw, wsum);
    // main: 1536 blocks (24 z x 64 segs of 8 rows), XCD-chunked decode
    ncc_f8<<<dim3(1536, 1, 1), 64, 0, stream>>>(acw, rsw, wsum);
    // finalize: one wave
    fin_f4<<<dim3(1, 1, 1), 64, 0, stream>>>(wsum, out);
}

// Round 10
// 129.815 us; speedup vs baseline: 1.1848x; 1.0149x over previous
//
#include <hip/hip_runtime.h>
#include <hip/hip_fp16.h>

#define HH 512
#define WW 512
#define HW (HH*WW)
#define EPV 1e-20f

// R19: prep raw-row ring -- one source load-pair/step instead of three
// (R18 prep FETCH 114MB for a 40MB input = 3 reload fifos x halo; ring[8]
// gives add row (slot t&7) AND center row r-4 (slot (t+4)&7) from one load;
// subtract r-8 keeps a 2-slack fifo, value-identical -> exact telescoping).
// ncc: subtract prefetch 1->2-slack ping-pong (L2 latency cover).
// Keeps: 8-col centered windows (7bp/8cols), fp16 intermediates,
// amdgpu_waves_per_eu pins (prep (3,3) ~163 regs, ncc (2,2)), XCD-chunked
// ncc, per-z wsum + fin, barrier-free.

__device__ __forceinline__ float bpl(int addr, float v) {
    return __int_as_float(__builtin_amdgcn_ds_bpermute(addr, __float_as_int(v)));
}
__device__ __forceinline__ int rcl(int r) { return min(max(r, 0), HH - 1); }

__device__ __forceinline__ float4 h2f4(uint2 r) {
    __half2 lo = *(__half2*)&r.x, hi = *(__half2*)&r.y;
    float2 a = __half22float2(lo), b = __half22float2(hi);
    return make_float4(a.x, a.y, b.x, b.y);
}
__device__ __forceinline__ uint2 f2h4(float4 v) {
    __half2 lo = __floats2half2_rn(v.x, v.y);
    __half2 hi = __floats2half2_rn(v.z, v.w);
    uint2 r;
    r.x = *(unsigned int*)&lo;
    r.y = *(unsigned int*)&hi;
    return r;
}
__device__ __forceinline__ uint4 pack8(float4 a, float4 b) {
    uint2 lo = f2h4(a), hi = f2h4(b);
    return make_uint4(lo.x, lo.y, hi.x, hi.y);
}
__device__ __forceinline__ void unpack8(uint4 r, float4& a, float4& b) {
    a = h2f4(make_uint2(r.x, r.y));
    b = h2f4(make_uint2(r.z, r.w));
}

// ---------------- prep: raw -> fp16 centered (ac) + fp16 1/sqrt(var box) --
// One wave per (z, 8-row seg), full 512-col rows. 23 steps.
// r = y0-7+t (VA add row), c = r-4 (ac row), y = c-4 (rs row).
// Raw ring rg[8]: slot t&7 = row r (written at t-2); center = slot (t+4)&7.
__global__ void __launch_bounds__(64)
__attribute__((amdgpu_waves_per_eu(3, 3)))
prep_f8(const float* __restrict__ outs, const float* __restrict__ labs,
        __half* __restrict__ ac, __half* __restrict__ rs,
        float* __restrict__ wsum)
{
    const int l = threadIdx.x;
    if (blockIdx.x == 0 && blockIdx.y == 0 && l < 24)
        wsum[l * 64] = 0.f;                   // zero per-z partial slots
    const int y0 = 8 * blockIdx.x;
    const int z  = blockIdx.y;

    const float* src = (z < 24) ? outs + z * HW : labs + (z - 24) * HW;
    __half* acd = ac + z * HW;
    __half* rsd = rs + z * HW;

    const int   col = 8 * l;
    const int   aL1 = ((l - 1) & 63) << 2;
    const int   aR1 = ((l + 1) & 63) << 2;
    const float lmE = (l > 0)  ? 1.f : 0.f;
    const float rmE = (l < 63) ? 1.f : 0.f;

    float4 rgA[8], rgB[8];   // raw ring (rows r-5..r+2 at step t)
    float4 fOA[2], fOB[2];   // subtract row r-8 (2-slack fifo)
    uint4  pk[8];            // packed-fp16 ac ring (variance subtract)
    float4 VAa = {0,0,0,0}, VAb = {0,0,0,0};
    float4 Vqa = {0,0,0,0}, Vqb = {0,0,0,0};
    #pragma unroll
    for (int k = 0; k < 8; ++k) {
        rgA[k] = make_float4(0,0,0,0); rgB[k] = make_float4(0,0,0,0);
        pk[k]  = make_uint4(0,0,0,0);
    }
    fOA[0] = fOA[1] = fOB[0] = fOB[1] = make_float4(0,0,0,0);
    rgA[0] = *(const float4*)&src[rcl(y0 - 7) * WW + col];
    rgB[0] = *(const float4*)&src[rcl(y0 - 7) * WW + col + 4];
    rgA[1] = *(const float4*)&src[rcl(y0 - 6) * WW + col];
    rgB[1] = *(const float4*)&src[rcl(y0 - 6) * WW + col + 4];

    auto step = [&](const int t) {
        const int   r  = y0 - 7 + t;
        const float rm = (r >= 0 && r < HH) ? 1.f : 0.f;
        {   // VA += raw(r)  (ring slot t&7, written at t-2)
            float4 ra = rgA[t & 7], rb = rgB[t & 7];
            VAa.x += ra.x*rm; VAa.y += ra.y*rm; VAa.z += ra.z*rm; VAa.w += ra.w*rm;
            VAb.x += rb.x*rm; VAb.y += rb.y*rm; VAb.z += rb.z*rm; VAb.w += rb.w*rm;
        }
        if (t >= 8) {   // VA -= raw(r-8)  (fifo; value-identical to ring's old)
            const float rm8 = ((r - 8) >= 0 && (r - 8) < HH) ? 1.f : 0.f;
            float4 oa = fOA[t & 1], ob = fOB[t & 1];
            VAa.x -= oa.x*rm8; VAa.y -= oa.y*rm8; VAa.z -= oa.z*rm8; VAa.w -= oa.w*rm8;
            VAb.x -= ob.x*rm8; VAb.y -= ob.y*rm8; VAb.z -= ob.z*rm8; VAb.w -= ob.w*rm8;
        }
        if (t <= 20) {                        // prefetch row r+2 into (t+2)&7
            const int rn = rcl(r + 2);
            rgA[(t + 2) & 7] = *(const float4*)&src[rn * WW + col];
            rgB[(t + 2) & 7] = *(const float4*)&src[rn * WW + col + 4];
        }
        if (t >= 6 && t <= 20) {              // prefetch subtract row (r+2)-8
            const int ro = rcl(r - 6);
            fOA[t & 1] = *(const float4*)&src[ro * WW + col];
            fOB[t & 1] = *(const float4*)&src[ro * WW + col + 4];
        }
        if (t >= 8) {
            const int   c  = r - 4;
            const float cm = (c >= 0 && c < HH) ? 1.f : 0.f;
            // centered 8-wide window on VA (mean box, 64 px)
            float p1 = VAa.x, p2 = p1+VAa.y, p3 = p2+VAa.z, p4 = p3+VAa.w;
            float p5 = p4+VAb.x, p6 = p5+VAb.y, p7 = p6+VAb.z, tt = p7+VAb.w;
            float s1 = VAb.w, s2 = VAb.z+s1, s3 = VAb.y+s2;
            float L1 = bpl(aL1, s1)*lmE, L2 = bpl(aL1, s2)*lmE, L3 = bpl(aL1, s3)*lmE;
            float R1 = bpl(aR1, p1)*rmE, R2 = bpl(aR1, p2)*rmE;
            float R3 = bpl(aR1, p3)*rmE, R4 = bpl(aR1, p4)*rmE;
            // raw row c from the ring: slot (t+4)&7 == (t-4)&7 (written t-6)
            float4 rc0 = rgA[(t + 4) & 7], rc1 = rgB[(t + 4) & 7];
            float4 aL4, aH4;
            aL4.x = (rc0.x - (L3+p5)    * (1.f/64.f)) * cm;
            aL4.y = (rc0.y - (L2+p6)    * (1.f/64.f)) * cm;
            aL4.z = (rc0.z - (L1+p7)    * (1.f/64.f)) * cm;
            aL4.w = (rc0.w - tt         * (1.f/64.f)) * cm;
            aH4.x = (rc1.x - (tt-p1+R1) * (1.f/64.f)) * cm;
            aH4.y = (rc1.y - (tt-p2+R2) * (1.f/64.f)) * cm;
            aH4.z = (rc1.z - (tt-p3+R3) * (1.f/64.f)) * cm;
            aH4.w = (rc1.w - (tt-p4+R4) * (1.f/64.f)) * cm;
            uint4 pkNew = pack8(aL4, aH4);
            if (t >= 11 && t <= 18)           // store own 8 rows
                *(uint4*)&acd[c * WW + col] = pkNew;
            // variance slide on the ROUNDED values (exact telescoping)
            float4 qnL, qnH; unpack8(pkNew, qnL, qnH);
            Vqa.x += qnL.x*qnL.x; Vqa.y += qnL.y*qnL.y;
            Vqa.z += qnL.z*qnL.z; Vqa.w += qnL.w*qnL.w;
            Vqb.x += qnH.x*qnH.x; Vqb.y += qnH.y*qnH.y;
            Vqb.z += qnH.z*qnH.z; Vqb.w += qnH.w*qnH.w;
            if (t >= 16) {                    // subtract sq(ac(c-8))
                float4 oL, oH; unpack8(pk[t & 7], oL, oH);
                Vqa.x -= oL.x*oL.x; Vqa.y -= oL.y*oL.y;
                Vqa.z -= oL.z*oL.z; Vqa.w -= oL.w*oL.w;
                Vqb.x -= oH.x*oH.x; Vqb.y -= oH.y*oH.y;
                Vqb.z -= oH.z*oH.z; Vqb.w -= oH.w*oH.w;
            }
            pk[t & 7] = pkNew;
            if (t >= 15 && t <= 22) {         // emit rs at row y = c-4
                const int y = c - 4;          // y in [y0, y0+7]
                float q1 = Vqa.x, q2 = q1+Vqa.y, q3 = q2+Vqa.z, q4 = q3+Vqa.w;
                float q5 = q4+Vqb.x, q6 = q5+Vqb.y, q7 = q6+Vqb.z, qt = q7+Vqb.w;
                float z1 = Vqb.w, z2 = Vqb.z+z1, z3 = Vqb.y+z2;
                float Lq1 = bpl(aL1, z1)*lmE, Lq2 = bpl(aL1, z2)*lmE, Lq3 = bpl(aL1, z3)*lmE;
                float Rq1 = bpl(aR1, q1)*rmE, Rq2 = bpl(aR1, q2)*rmE;
                float Rq3 = bpl(aR1, q3)*rmE, Rq4 = bpl(aR1, q4)*rmE;
                float4 rL, rH;
                rL.x = fminf(__frsqrt_rn(fmaxf(Lq3+q5,    EPV)), 60000.f);
                rL.y = fminf(__frsqrt_rn(fmaxf(Lq2+q6,    EPV)), 60000.f);
                rL.z = fminf(__frsqrt_rn(fmaxf(Lq1+q7,    EPV)), 60000.f);
                rL.w = fminf(__frsqrt_rn(fmaxf(qt,        EPV)), 60000.f);
                rH.x = fminf(__frsqrt_rn(fmaxf(qt-q1+Rq1, EPV)), 60000.f);
                rH.y = fminf(__frsqrt_rn(fmaxf(qt-q2+Rq2, EPV)), 60000.f);
                rH.z = fminf(__frsqrt_rn(fmaxf(qt-q3+Rq3, EPV)), 60000.f);
                rH.w = fminf(__frsqrt_rn(fmaxf(qt-q4+Rq4, EPV)), 60000.f);
                *(uint4*)&rsd[y * WW + col] = pack8(rL, rH);
            }
        }
    };
    #pragma unroll
    for (int t = 0; t < 23; ++t) step(t);
}

// ---------------- main: product boxes, full-width rows, 4 j per wave ------
// One wave per (z, 8-row seg). 15 steps. 1536 waves, XCD-chunked.
// Vp[j] += p(row c) - p(row c-8); subtract rows via 2-slack reload (exact
// fp16 telescoping). Emit window centered (7 bp / 8 cols / j).
__global__ void __launch_bounds__(64)
__attribute__((amdgpu_waves_per_eu(2, 2)))
ncc_f8(const __half* __restrict__ ac, const __half* __restrict__ rs,
       float* __restrict__ wsum)
{
    const int l   = threadIdx.x;
    const int n   = blockIdx.x;            // 0..1535
    const int xcd = n & 7;
    const int p   = n >> 3;                // 0..191
    const int zq  = p >> 6;                // 0..2
    const int seg = p & 63;                // 0..63
    const int z   = 3 * xcd + zq;          // b*6 + i
    const int b   = z / 6;
    const int y0  = 8 * seg;

    const __half* acp = ac + z * HW;
    const __half* sip = rs + z * HW;
    const __half* bcp[4]; const __half* sjp[4];
    #pragma unroll
    for (int j = 0; j < 4; ++j) {
        bcp[j] = ac + (24 + b * 4 + j) * HW;
        sjp[j] = rs + (24 + b * 4 + j) * HW;
    }

    const int   col = 8 * l;
    const int   aL1 = ((l - 1) & 63) << 2;
    const int   aR1 = ((l + 1) & 63) << 2;
    const float lmE = (l > 0)  ? 1.f : 0.f;
    const float rmE = (l < 63) ? 1.f : 0.f;

    uint4 fa[2], fb[4][2];                 // add rows (2-slack)
    uint4 oA[2], oB[4][2];                 // subtract rows (2-slack)
    {
        const int r0 = rcl(y0 - 3), r1 = rcl(y0 - 2);
        fa[0] = *(const uint4*)&acp[r0 * WW + col];
        fa[1] = *(const uint4*)&acp[r1 * WW + col];
        #pragma unroll
        for (int j = 0; j < 4; ++j) {
            fb[j][0] = *(const uint4*)&bcp[j][r0 * WW + col];
            fb[j][1] = *(const uint4*)&bcp[j][r1 * WW + col];
            oB[j][0] = make_uint4(0,0,0,0); oB[j][1] = make_uint4(0,0,0,0);
        }
        oA[0] = make_uint4(0,0,0,0); oA[1] = make_uint4(0,0,0,0);
    }

    float4 VpL[4], VpH[4];
    uint4 psiB[2], psjB[2][4];
    float4 xsL = make_float4(0,0,0,0), xsH = make_float4(0,0,0,0);
    #pragma unroll
    for (int j = 0; j < 4; ++j) {
        VpL[j] = make_float4(0,0,0,0); VpH[j] = make_float4(0,0,0,0);
        psjB[0][j] = make_uint4(0,0,0,0); psjB[1][j] = make_uint4(0,0,0,0);
    }
    psiB[0] = make_uint4(0,0,0,0); psiB[1] = make_uint4(0,0,0,0);

    auto step = [&](const int t) {
        const int   c  = y0 - 3 + t;                 // row being ADDED
        const float rm = (c >= 0 && c < HH) ? 1.f : 0.f;
        uint4 ar = fa[t & 1];
        uint4 br0 = fb[0][t & 1], br1 = fb[1][t & 1];
        uint4 br2 = fb[2][t & 1], br3 = fb[3][t & 1];
        uint4 arO = oA[t & 1];                       // row c-8 (valid t>=8)
        uint4 bo0 = oB[0][t & 1], bo1 = oB[1][t & 1];
        uint4 bo2 = oB[2][t & 1], bo3 = oB[3][t & 1];
        if (t <= 12) {                               // add-row prefetch
            const int rn = rcl(c + 2);
            fa[t & 1] = *(const uint4*)&acp[rn * WW + col];
            #pragma unroll
            for (int j = 0; j < 4; ++j)
                fb[j][t & 1] = *(const uint4*)&bcp[j][rn * WW + col];
        }
        if (t >= 6 && t <= 12) {                     // subtract-row prefetch
            const int ro = rcl(c - 6);               // used at t+2 (row c-6)
            oA[t & 1] = *(const uint4*)&acp[ro * WW + col];
            #pragma unroll
            for (int j = 0; j < 4; ++j)
                oB[j][t & 1] = *(const uint4*)&bcp[j][ro * WW + col];
        }
        {   // add products of row c
            float4 avL, avH; unpack8(ar, avL, avH);
            avL.x *= rm; avL.y *= rm; avL.z *= rm; avL.w *= rm;
            avH.x *= rm; avH.y *= rm; avH.z *= rm; avH.w *= rm;
            float4 bL, bH;
            unpack8(br0, bL, bH);
            VpL[0].x += avL.x*bL.x; VpL[0].y += avL.y*bL.y; VpL[0].z += avL.z*bL.z; VpL[0].w += avL.w*bL.w;
            VpH[0].x += avH.x*bH.x; VpH[0].y += avH.y*bH.y; VpH[0].z += avH.z*bH.z; VpH[0].w += avH.w*bH.w;
            unpack8(br1, bL, bH);
            VpL[1].x += avL.x*bL.x; VpL[1].y += avL.y*bL.y; VpL[1].z += avL.z*bL.z; VpL[1].w += avL.w*bL.w;
            VpH[1].x += avH.x*bH.x; VpH[1].y += avH.y*bH.y; VpH[1].z += avH.z*bH.z; VpH[1].w += avH.w*bH.w;
            unpack8(br2, bL, bH);
            VpL[2].x += avL.x*bL.x; VpL[2].y += avL.y*bL.y; VpL[2].z += avL.z*bL.z; VpL[2].w += avL.w*bL.w;
            VpH[2].x += avH.x*bH.x; VpH[2].y += avH.y*bH.y; VpH[2].z += avH.z*bH.z; VpH[2].w += avH.w*bH.w;
            unpack8(br3, bL, bH);
            VpL[3].x += avL.x*bL.x; VpL[3].y += avL.y*bL.y; VpL[3].z += avL.z*bL.z; VpL[3].w += avL.w*bL.w;
            VpH[3].x += avH.x*bH.x; VpH[3].y += avH.y*bH.y; VpH[3].z += avH.z*bH.z; VpH[3].w += avH.w*bH.w;
        }
        if (t >= 8) {   // subtract products of row c-8
            const float rmO = ((c - 8) >= 0) ? 1.f : 0.f;
            float4 avL, avH; unpack8(arO, avL, avH);
            avL.x *= rmO; avL.y *= rmO; avL.z *= rmO; avL.w *= rmO;
            avH.x *= rmO; avH.y *= rmO; avH.z *= rmO; avH.w *= rmO;
            float4 bL, bH;
            unpack8(bo0, bL, bH);
            VpL[0].x -= avL.x*bL.x; VpL[0].y -= avL.y*bL.y; VpL[0].z -= avL.z*bL.z; VpL[0].w -= avL.w*bL.w;
            VpH[0].x -= avH.x*bH.x; VpH[0].y -= avH.y*bH.y; VpH[0].z -= avH.z*bH.z; VpH[0].w -= avH.w*bH.w;
            unpack8(bo1, bL, bH);
            VpL[1].x -= avL.x*bL.x; VpL[1].y -= avL.y*bL.y; VpL[1].z -= avL.z*bL.z; VpL[1].w -= avL.w*bL.w;
            VpH[1].x -= avH.x*bH.x; VpH[1].y -= avH.y*bH.y; VpH[1].z -= avH.z*bH.z; VpH[1].w -= avH.w*bH.w;
            unpack8(bo2, bL, bH);
            VpL[2].x -= avL.x*bL.x; VpL[2].y -= avL.y*bL.y; VpL[2].z -= avL.z*bL.z; VpL[2].w -= avL.w*bL.w;
            VpH[2].x -= avH.x*bH.x; VpH[2].y -= avH.y*bH.y; VpH[2].z -= avH.z*bH.z; VpH[2].w -= avH.w*bH.w;
            unpack8(bo3, bL, bH);
            VpL[3].x -= avL.x*bL.x; VpL[3].y -= avL.y*bL.y; VpL[3].z -= avL.z*bL.z; VpL[3].w -= avL.w*bL.w;
            VpH[3].x -= avH.x*bH.x; VpH[3].y -= avH.y*bH.y; VpH[3].z -= avH.z*bH.z; VpH[3].w -= avH.w*bH.w;
        }
        if (t >= 7 && t <= 14) {   // emit row y = y0+t-7 (all cols valid)
            float4 pL, pH; unpack8(psiB[t & 1], pL, pH);
            float4 mmL = make_float4(-1,-1,-1,-1), mmH = make_float4(-1,-1,-1,-1);
            #pragma unroll
            for (int j = 0; j < 4; ++j) {
                float q1 = VpL[j].x, q2 = q1+VpL[j].y, q3 = q2+VpL[j].z, q4 = q3+VpL[j].w;
                float q5 = q4+VpH[j].x, q6 = q5+VpH[j].y, q7 = q6+VpH[j].z, q8 = q7+VpH[j].w;
                float s1 = VpH[j].w, s2 = VpH[j].z+s1, s3 = VpH[j].y+s2;
                float L1 = bpl(aL1, s1)*lmE, L2 = bpl(aL1, s2)*lmE, L3 = bpl(aL1, s3)*lmE;
                float R1 = bpl(aR1, q1)*rmE, R2 = bpl(aR1, q2)*rmE;
                float R3 = bpl(aR1, q3)*rmE, R4 = bpl(aR1, q4)*rmE;
                float4 sL, sH; unpack8(psjB[t & 1][j], sL, sH);
                mmL.x = fmaxf(mmL.x, (L3+q5)    * (pL.x*sL.x));
                mmL.y = fmaxf(mmL.y, (L2+q6)    * (pL.y*sL.y));
                mmL.z = fmaxf(mmL.z, (L1+q7)    * (pL.z*sL.z));
                mmL.w = fmaxf(mmL.w, q8         * (pL.w*sL.w));
                mmH.x = fmaxf(mmH.x, (q8-q1+R1) * (pH.x*sH.x));
                mmH.y = fmaxf(mmH.y, (q8-q2+R2) * (pH.y*sH.y));
                mmH.z = fmaxf(mmH.z, (q8-q3+R3) * (pH.z*sH.z));
                mmH.w = fmaxf(mmH.w, (q8-q4+R4) * (pH.w*sH.w));
            }
            xsL.x += 1.f - fminf(mmL.x, 1.f);
            xsL.y += 1.f - fminf(mmL.y, 1.f);
            xsL.z += 1.f - fminf(mmL.z, 1.f);
            xsL.w += 1.f - fminf(mmL.w, 1.f);
            xsH.x += 1.f - fminf(mmH.x, 1.f);
            xsH.y += 1.f - fminf(mmH.y, 1.f);
            xsH.z += 1.f - fminf(mmH.z, 1.f);
            xsH.w += 1.f - fminf(mmH.w, 1.f);
        }
        if (t >= 5 && t <= 12) {   // denom prefetch, 2-step slack
            const int yn = min(y0 + t - 5, HH - 1);
            psiB[t & 1] = *(const uint4*)&sip[yn * WW + col];
            #pragma unroll
            for (int j = 0; j < 4; ++j)
                psjB[t & 1][j] = *(const uint4*)&sjp[j][yn * WW + col];
        }
    };
    #pragma unroll
    for (int t = 0; t < 15; ++t) step(t);

    float xt = xsL.x + xsL.y + xsL.z + xsL.w + xsH.x + xsH.y + xsH.z + xsH.w;
    #pragma unroll
    for (int off = 32; off > 0; off >>= 1) xt += __shfl_down(xt, off);
    if (l == 0) atomicAdd(&wsum[z * 64], xt);
}

// ---------------- finalize: 24 partials -> 25 outputs ---------------------
__global__ void fin_f4(const float* __restrict__ wsum, float* __restrict__ out)
{
    const int l = threadIdx.x;
    float v = (l < 24) ? wsum[l * 64] : 0.f;
    if (l < 24) out[1 + l] = v * (1.f / (float)HW);
    #pragma unroll
    for (int off = 32; off > 0; off >>= 1) v += __shfl_down(v, off);
    if (l == 0) out[0] = v * (1.f / (24.f * (float)HW));
}

extern "C" void kernel_launch(void* const* d_in, const int* in_sizes, int n_in,
                              void* d_out, int out_size, void* d_ws, size_t ws_size,
                              hipStream_t stream) {
    const float* outs = (const float*)d_in[0];   // (4,6,512,512)
    const float* labs = (const float*)d_in[1];   // (4,4,512,512)
    float* out = (float*)d_out;                  // 25 floats
    float* ws  = (float*)d_ws;

    __half* acw  = (__half*)ws;            // 40*HW halves (a:0..23, b:24..39)
    __half* rsw  = (__half*)ws + 40 * HW;  // 40*HW halves (fp16 1/sqrt(var))
    float*  wsum = ws + 40 * HW;           // floats: after the two half arrays

    // prep: 64 segs(8 rows) x 40 images, full-width waves (also zeroes wsum)
    prep_f8<<<dim3(64, 40), 64, 0, stream>>>(outs, labs, acw, rsw, wsum);
    // main: 1536 blocks (24 z x 64 segs of 8 rows), XCD-chunked decode
    ncc_f8<<<dim3(1536, 1, 1), 64, 0, stream>>>(acw, rsw, wsum);
    // finalize: one wave
    fin_f4<<<dim3(1, 1, 1), 64, 0, stream>>>(wsum, out);
}